// Round 1
// baseline (351.625 us; speedup 1.0000x reference)
//
#include <hip/hip_runtime.h>
#include <hip/hip_bf16.h>
#include <stdint.h>

typedef __attribute__((ext_vector_type(8))) short short8;
typedef __attribute__((ext_vector_type(4))) float f32x4;

// Problem constants
#define BATCH 4
#define SEQ   2048
#define EMB   1024
#define HEADS 16
#define DHEAD 64
#define MROWS (BATCH * SEQ)   // 8192

__device__ inline unsigned short f2bf(float f) {
    unsigned int u = __float_as_uint(f);
    unsigned int r = (u + 0x7fffu + ((u >> 16) & 1u)) >> 16;
    return (unsigned short)r;
}

// ---------------- pack f32 -> bf16, 8 elems/thread ----------------
__global__ __launch_bounds__(256) void pack_bf16(const float* __restrict__ src,
                                                 unsigned short* __restrict__ dst,
                                                 int n) {
    int i = (blockIdx.x * 256 + threadIdx.x) * 8;
    if (i >= n) return;
    const float4* s = reinterpret_cast<const float4*>(src + i);
    float4 f0 = s[0];
    float4 f1 = s[1];
    union { unsigned short u[8]; short8 v; } o;
    o.u[0] = f2bf(f0.x); o.u[1] = f2bf(f0.y); o.u[2] = f2bf(f0.z); o.u[3] = f2bf(f0.w);
    o.u[4] = f2bf(f1.x); o.u[5] = f2bf(f1.y); o.u[6] = f2bf(f1.z); o.u[7] = f2bf(f1.w);
    *reinterpret_cast<short8*>(dst + i) = o.v;
}

// ---------------- GEMM: C[m,e] = sum_k A[m,k] * B[e,k]  (NT, bf16 in) ----
// MODE 0: store bf16 to Cb.  MODE 1: store f32 to out, scaled by diag.
#define BM 128
#define BN 128
#define BK 32
#define LDK 40  // +8 bf16 pad (16B) keeps 16B alignment, kills bank conflicts

template <int MODE>
__global__ __launch_bounds__(256) void gemm_bt(const short* __restrict__ A,
                                               const short* __restrict__ Bm,
                                               unsigned short* __restrict__ Cb,
                                               float* __restrict__ out,
                                               const float* __restrict__ dgp,
                                               int M, int N, int K) {
    __shared__ short As[BM][LDK];
    __shared__ short Bs[BN][LDK];
    const int m0 = blockIdx.x * BM;
    const int n0 = blockIdx.y * BN;
    const int t = threadIdx.x;
    const int lane = t & 63;
    const int w = t >> 6;          // 4 waves
    const int wr = w >> 1, wc = w & 1;   // 2x2 wave grid, 64x64 per wave

    f32x4 acc[4][4] = {};

    const int srow = t >> 2;            // 0..63
    const int sc8 = (t & 3) * 8;        // 0,8,16,24
    const int kq = (lane >> 4) * 8;     // k sub-offset for fragments

    for (int k0 = 0; k0 < K; k0 += BK) {
        // stage A tile (128x32) and B tile (128x32)
        *(short8*)&As[srow][sc8]      = *(const short8*)&A[(m0 + srow) * K + k0 + sc8];
        *(short8*)&As[srow + 64][sc8] = *(const short8*)&A[(m0 + srow + 64) * K + k0 + sc8];
        *(short8*)&Bs[srow][sc8]      = *(const short8*)&Bm[(n0 + srow) * K + k0 + sc8];
        *(short8*)&Bs[srow + 64][sc8] = *(const short8*)&Bm[(n0 + srow + 64) * K + k0 + sc8];
        __syncthreads();

        short8 a[4], b[4];
#pragma unroll
        for (int i = 0; i < 4; i++)
            a[i] = *(const short8*)&As[wr * 64 + i * 16 + (lane & 15)][kq];
#pragma unroll
        for (int j = 0; j < 4; j++)
            b[j] = *(const short8*)&Bs[wc * 64 + j * 16 + (lane & 15)][kq];
#pragma unroll
        for (int i = 0; i < 4; i++)
#pragma unroll
            for (int j = 0; j < 4; j++)
                acc[i][j] = __builtin_amdgcn_mfma_f32_16x16x32_bf16(a[i], b[j], acc[i][j], 0, 0, 0);
        __syncthreads();
    }

    // epilogue: C[i][j] lane layout: col = lane&15, row = 4*(lane>>4)+r
    const int gr_base = m0 + wr * 64 + (lane >> 4) * 4;
    const int gc_base = n0 + wc * 64 + (lane & 15);
#pragma unroll
    for (int i = 0; i < 4; i++) {
#pragma unroll
        for (int j = 0; j < 4; j++) {
            const int col = gc_base + j * 16;
#pragma unroll
            for (int r = 0; r < 4; r++) {
                const int grow = gr_base + i * 16 + r;
                if (MODE == 0) {
                    Cb[grow * N + col] = f2bf(acc[i][j][r]);
                } else {
                    const int bb = grow >> 11;       // /2048
                    const int nn = grow & 2047;
                    const int hh = col >> 6;         // /64
                    const float d = dgp[((bb << 4) + hh) * SEQ + nn];
                    out[grow * N + col] = acc[i][j][r] * d;
                }
            }
        }
    }
}

// ---------------- diag kernel: diag[b,h,n] = exp(s_nn)/sum_m exp(s_nm) ----
// block: one (b,h, 64-row tile). 4 waves x 16 rows. scores via MFMA 16x16x32.
__global__ __launch_bounds__(256) void diag_kernel(const short* __restrict__ Q,
                                                   const short* __restrict__ Km,
                                                   float* __restrict__ dgp) {
    const int blk = blockIdx.x;
    const int nt = blk & 31;       // 32 tiles of 64 rows over SEQ
    const int bh = blk >> 5;       // 0..63
    const int b = bh >> 4, h = bh & 15;
    const int t = threadIdx.x;
    const int lane = t & 63;
    const int w = t >> 6;
    const int n0w = nt * 64 + w * 16;
    const int kq = (lane >> 4) * 8;

    // A fragments: this wave's 16 q-rows, k=0..63 (two K=32 chunks), held in regs
    const int qrow = b * SEQ + n0w + (lane & 15);
    const short* qbase = Q + qrow * EMB + h * DHEAD + kq;
    const short8 a0 = *(const short8*)(qbase);
    const short8 a1 = *(const short8*)(qbase + 32);

    float ssum[4] = {0.f, 0.f, 0.f, 0.f};
    float sdiag = 0.f;
    const int tdiag = n0w >> 4;

    const short* kbase = Km + (b * SEQ + (lane & 15)) * EMB + h * DHEAD + kq;

#pragma unroll 2
    for (int tt = 0; tt < SEQ / 16; ++tt) {
        const short* kp = kbase + tt * 16 * EMB;
        const short8 b0 = *(const short8*)(kp);
        const short8 b1 = *(const short8*)(kp + 32);
        f32x4 c = {};
        c = __builtin_amdgcn_mfma_f32_16x16x32_bf16(a0, b0, c, 0, 0, 0);
        c = __builtin_amdgcn_mfma_f32_16x16x32_bf16(a1, b1, c, 0, 0, 0);
        if (tt == tdiag) {
            const int il = (lane >> 4) * 4;
            const int r = (lane & 15) - il;
            if (r >= 0 && r < 4) sdiag = c[r];
        }
#pragma unroll
        for (int r = 0; r < 4; r++) {
            ssum[r] += __expf(c[r] * 0.125f);
        }
    }

    // reduce partial sums across the 16-lane column groups
#pragma unroll
    for (int r = 0; r < 4; r++) {
        float v = ssum[r];
        v += __shfl_xor(v, 1);
        v += __shfl_xor(v, 2);
        v += __shfl_xor(v, 4);
        v += __shfl_xor(v, 8);
        ssum[r] = v;
    }

    const int il = (lane >> 4) * 4;
    const int j = lane & 15;
    const int r = j - il;
    if (r >= 0 && r < 4) {
        // this lane holds s_nn for row i=j and the full denom in ssum[r]
        const float dg = __expf(sdiag * 0.125f) / ssum[r];
        dgp[bh * SEQ + n0w + j] = dg;
    }
}

extern "C" void kernel_launch(void* const* d_in, const int* in_sizes, int n_in,
                              void* d_out, int out_size, void* d_ws, size_t ws_size,
                              hipStream_t stream) {
    const float* x  = (const float*)d_in[0];
    const float* Wq = (const float*)d_in[1];
    const float* Wk = (const float*)d_in[2];
    const float* Wv = (const float*)d_in[3];
    float* out = (float*)d_out;
    char* ws = (char*)d_ws;

    const size_t xb_off  = 0;
    const size_t wq_off  = xb_off + (size_t)MROWS * EMB * 2;        // 16777216
    const size_t wk_off  = wq_off + (size_t)EMB * EMB * 2;          // +2MB
    const size_t wv_off  = wk_off + (size_t)EMB * EMB * 2;
    const size_t q_off   = wv_off + (size_t)EMB * EMB * 2;
    const size_t k_off   = q_off + (size_t)MROWS * EMB * 2;
    const size_t dg_off  = k_off + (size_t)MROWS * EMB * 2;

    short* xb  = (short*)(ws + xb_off);
    short* wqb = (short*)(ws + wq_off);
    short* wkb = (short*)(ws + wk_off);
    short* wvb = (short*)(ws + wv_off);
    short* Qb  = (short*)(ws + q_off);
    short* Kb  = (short*)(ws + k_off);
    float* dgp = (float*)(ws + dg_off);

    const int nx = MROWS * EMB;    // 8388608
    const int nw = EMB * EMB;      // 1048576

    pack_bf16<<<nx / (256 * 8), 256, 0, stream>>>(x, (unsigned short*)xb, nx);
    pack_bf16<<<nw / (256 * 8), 256, 0, stream>>>(Wq, (unsigned short*)wqb, nw);
    pack_bf16<<<nw / (256 * 8), 256, 0, stream>>>(Wk, (unsigned short*)wkb, nw);
    pack_bf16<<<nw / (256 * 8), 256, 0, stream>>>(Wv, (unsigned short*)wvb, nw);

    dim3 grid(MROWS / BM, EMB / BN);
    gemm_bt<0><<<grid, 256, 0, stream>>>(xb, wqb, (unsigned short*)Qb, nullptr, nullptr, MROWS, EMB, EMB);
    gemm_bt<0><<<grid, 256, 0, stream>>>(xb, wkb, (unsigned short*)Kb, nullptr, nullptr, MROWS, EMB, EMB);

    diag_kernel<<<BATCH * HEADS * (SEQ / 64), 256, 0, stream>>>(Qb, Kb, dgp);

    gemm_bt<1><<<grid, 256, 0, stream>>>(xb, wvb, nullptr, out, dgp, MROWS, EMB, EMB);

    // output 1: x passthrough
    hipMemcpyAsync(out + (size_t)MROWS * EMB, x, (size_t)MROWS * EMB * sizeof(float),
                   hipMemcpyDeviceToDevice, stream);
}

// Round 2
// 190.580 us; speedup vs baseline: 1.8450x; 1.8450x over previous
//
#include <hip/hip_runtime.h>
#include <hip/hip_bf16.h>
#include <stdint.h>

typedef __attribute__((ext_vector_type(8))) short short8;
typedef __attribute__((ext_vector_type(4))) float f32x4;

// Problem constants
#define BATCH 4
#define SEQ   2048
#define EMB   1024
#define HEADS 16
#define DHEAD 64
#define MROWS (BATCH * SEQ)   // 8192

__device__ inline unsigned short f2bf(float f) {
    unsigned int u = __float_as_uint(f);
    unsigned int r = (u + 0x7fffu + ((u >> 16) & 1u)) >> 16;
    return (unsigned short)r;
}

// ---------------- pack f32 -> bf16, 8 elems/thread ----------------
__global__ __launch_bounds__(256) void pack_bf16(const float* __restrict__ src,
                                                 unsigned short* __restrict__ dst,
                                                 int n) {
    int i = (blockIdx.x * 256 + threadIdx.x) * 8;
    if (i >= n) return;
    const float4* s = reinterpret_cast<const float4*>(src + i);
    float4 f0 = s[0];
    float4 f1 = s[1];
    union { unsigned short u[8]; short8 v; } o;
    o.u[0] = f2bf(f0.x); o.u[1] = f2bf(f0.y); o.u[2] = f2bf(f0.z); o.u[3] = f2bf(f0.w);
    o.u[4] = f2bf(f1.x); o.u[5] = f2bf(f1.y); o.u[6] = f2bf(f1.z); o.u[7] = f2bf(f1.w);
    *reinterpret_cast<short8*>(dst + i) = o.v;
}

// ---------------- GEMM: C[m,e] = sum_k A[m,k] * B[e,k]  (NT, bf16 in) ----
// MODE 0: store bf16 head-major [B*H][SEQ][DHEAD].  MODE 1: f32 out * diag.
#define BM 128
#define BN 128
#define BK 32
#define LDK 40  // +8 bf16 pad (16B) keeps 16B alignment, kills bank conflicts

template <int MODE>
__global__ __launch_bounds__(256) void gemm_bt(const short* __restrict__ A,
                                               const short* __restrict__ Bm,
                                               unsigned short* __restrict__ Cb,
                                               float* __restrict__ out,
                                               const float* __restrict__ dgp,
                                               int M, int N, int K) {
    __shared__ short As[BM][LDK];
    __shared__ short Bs[BN][LDK];
    const int m0 = blockIdx.x * BM;
    const int n0 = blockIdx.y * BN;
    const int t = threadIdx.x;
    const int lane = t & 63;
    const int w = t >> 6;          // 4 waves
    const int wr = w >> 1, wc = w & 1;   // 2x2 wave grid, 64x64 per wave

    f32x4 acc[4][4] = {};

    const int srow = t >> 2;            // 0..63
    const int sc8 = (t & 3) * 8;        // 0,8,16,24
    const int kq = (lane >> 4) * 8;     // k sub-offset for fragments

    for (int k0 = 0; k0 < K; k0 += BK) {
        // stage A tile (128x32) and B tile (128x32)
        *(short8*)&As[srow][sc8]      = *(const short8*)&A[(m0 + srow) * K + k0 + sc8];
        *(short8*)&As[srow + 64][sc8] = *(const short8*)&A[(m0 + srow + 64) * K + k0 + sc8];
        *(short8*)&Bs[srow][sc8]      = *(const short8*)&Bm[(n0 + srow) * K + k0 + sc8];
        *(short8*)&Bs[srow + 64][sc8] = *(const short8*)&Bm[(n0 + srow + 64) * K + k0 + sc8];
        __syncthreads();

        short8 a[4], b[4];
#pragma unroll
        for (int i = 0; i < 4; i++)
            a[i] = *(const short8*)&As[wr * 64 + i * 16 + (lane & 15)][kq];
#pragma unroll
        for (int j = 0; j < 4; j++)
            b[j] = *(const short8*)&Bs[wc * 64 + j * 16 + (lane & 15)][kq];
#pragma unroll
        for (int i = 0; i < 4; i++)
#pragma unroll
            for (int j = 0; j < 4; j++)
                acc[i][j] = __builtin_amdgcn_mfma_f32_16x16x32_bf16(a[i], b[j], acc[i][j], 0, 0, 0);
        __syncthreads();
    }

    // epilogue: C[i][j] lane layout: col = lane&15, row = 4*(lane>>4)+r
    const int gr_base = m0 + wr * 64 + (lane >> 4) * 4;
    const int gc_base = n0 + wc * 64 + (lane & 15);
#pragma unroll
    for (int i = 0; i < 4; i++) {
#pragma unroll
        for (int j = 0; j < 4; j++) {
            const int col = gc_base + j * 16;
#pragma unroll
            for (int r = 0; r < 4; r++) {
                const int grow = gr_base + i * 16 + r;
                const int bb = grow >> 11;       // /2048
                const int nn = grow & 2047;
                const int hh = col >> 6;         // /64
                if (MODE == 0) {
                    // head-major: [(bb*16+hh)][nn][col&63]
                    const int dd = col & 63;
                    Cb[(((size_t)((bb << 4) + hh) * SEQ + nn) << 6) + dd] = f2bf(acc[i][j][r]);
                } else {
                    const float d = dgp[((bb << 4) + hh) * SEQ + nn];
                    out[grow * N + col] = acc[i][j][r] * d;
                }
            }
        }
    }
}

// ---------------- diag kernel v2 ----------------------------------------
// Qh/Kh head-major [64][2048][64] bf16. Block = (bh, 128-q-row tile),
// 512 threads = 8 waves, each wave owns 16 q-rows. K staged in LDS tiles
// of 128 rows, shared by all 8 waves; single barrier per tile (disjoint
// double buffers).
#define KT 128          // k-rows per LDS tile
#define LDKD 72         // 64 + 8 pad shorts -> 144B row stride, 2-way max alias

__global__ __launch_bounds__(512) void diag_kernel(const short* __restrict__ Qh,
                                                   const short* __restrict__ Kh,
                                                   float* __restrict__ dgp) {
    const int bh = blockIdx.x >> 4;     // 0..63
    const int qt = blockIdx.x & 15;     // 16 q-tiles of 128 rows
    __shared__ short Ks[2][KT][LDKD];

    const int t = threadIdx.x;
    const int lane = t & 63;
    const int w = t >> 6;               // 0..7
    const int kq = (lane >> 4) * 8;

    const short* Kbh = Kh + (size_t)bh * SEQ * DHEAD;
    const short* Qbh = Qh + (size_t)bh * SEQ * DHEAD;

    // Q fragments for this wave's 16 rows (depth 0..63 in two K=32 chunks)
    const int qrow = qt * 128 + w * 16 + (lane & 15);
    const short8 a0 = *(const short8*)(Qbh + qrow * DHEAD + kq);
    const short8 a1 = *(const short8*)(Qbh + qrow * DHEAD + kq + 32);

    // staging map: 512 threads cover 128 rows x 64 cols in 2 short8 each
    const int r0 = t >> 3;              // 0..63
    const int c0 = (t & 7) * 8;         // 0..56

    // stage tile 0
    *(short8*)&Ks[0][r0][c0]      = *(const short8*)&Kbh[r0 * DHEAD + c0];
    *(short8*)&Ks[0][r0 + 64][c0] = *(const short8*)&Kbh[(r0 + 64) * DHEAD + c0];
    __syncthreads();

    float ssum[4] = {0.f, 0.f, 0.f, 0.f};
    float sdiag = 0.f;
    int buf = 0;

    for (int kt = 0; kt < SEQ / KT; ++kt) {
        short8 p0, p1;
        if (kt < SEQ / KT - 1) {
            const short* src = Kbh + (kt + 1) * KT * DHEAD;
            p0 = *(const short8*)&src[r0 * DHEAD + c0];
            p1 = *(const short8*)&src[(r0 + 64) * DHEAD + c0];
        }
#pragma unroll
        for (int sub = 0; sub < 8; ++sub) {
            const int krow = sub * 16 + (lane & 15);
            const short8 b0 = *(const short8*)&Ks[buf][krow][kq];
            const short8 b1 = *(const short8*)&Ks[buf][krow][kq + 32];
            f32x4 c = {};
            c = __builtin_amdgcn_mfma_f32_16x16x32_bf16(a0, b0, c, 0, 0, 0);
            c = __builtin_amdgcn_mfma_f32_16x16x32_bf16(a1, b1, c, 0, 0, 0);
            if (kt == qt && sub == w) {
                const int r = (lane & 15) - (lane >> 4) * 4;
                if (r >= 0 && r < 4) sdiag = c[r];
            }
#pragma unroll
            for (int r = 0; r < 4; ++r)
                ssum[r] += __expf(c[r] * 0.125f);
        }
        if (kt < SEQ / KT - 1) {
            // writes go to buf^1 (disjoint from reads of buf): one barrier
            __syncthreads();
            *(short8*)&Ks[buf ^ 1][r0][c0]      = p0;
            *(short8*)&Ks[buf ^ 1][r0 + 64][c0] = p1;
            __syncthreads();
        }
        buf ^= 1;
    }

    // reduce partial sums across the 16-lane column groups
#pragma unroll
    for (int r = 0; r < 4; r++) {
        float v = ssum[r];
        v += __shfl_xor(v, 1);
        v += __shfl_xor(v, 2);
        v += __shfl_xor(v, 4);
        v += __shfl_xor(v, 8);
        ssum[r] = v;
    }

    const int j = lane & 15;
    const int r = j - (lane >> 4) * 4;
    if (r >= 0 && r < 4) {
        // this lane holds s_qq for row q = w*16 + j and the denom in ssum[r]
        const float dg = __expf(sdiag * 0.125f) / ssum[r];
        dgp[bh * SEQ + qt * 128 + w * 16 + j] = dg;
    }
}

extern "C" void kernel_launch(void* const* d_in, const int* in_sizes, int n_in,
                              void* d_out, int out_size, void* d_ws, size_t ws_size,
                              hipStream_t stream) {
    const float* x  = (const float*)d_in[0];
    const float* Wq = (const float*)d_in[1];
    const float* Wk = (const float*)d_in[2];
    const float* Wv = (const float*)d_in[3];
    float* out = (float*)d_out;
    char* ws = (char*)d_ws;

    const size_t xb_off  = 0;
    const size_t wq_off  = xb_off + (size_t)MROWS * EMB * 2;
    const size_t wk_off  = wq_off + (size_t)EMB * EMB * 2;
    const size_t wv_off  = wk_off + (size_t)EMB * EMB * 2;
    const size_t q_off   = wv_off + (size_t)EMB * EMB * 2;
    const size_t k_off   = q_off + (size_t)MROWS * EMB * 2;
    const size_t dg_off  = k_off + (size_t)MROWS * EMB * 2;

    short* xb  = (short*)(ws + xb_off);
    short* wqb = (short*)(ws + wq_off);
    short* wkb = (short*)(ws + wk_off);
    short* wvb = (short*)(ws + wv_off);
    short* Qh  = (short*)(ws + q_off);
    short* Kh  = (short*)(ws + k_off);
    float* dgp = (float*)(ws + dg_off);

    const int nx = MROWS * EMB;    // 8388608
    const int nw = EMB * EMB;      // 1048576

    pack_bf16<<<nx / (256 * 8), 256, 0, stream>>>(x, (unsigned short*)xb, nx);
    pack_bf16<<<nw / (256 * 8), 256, 0, stream>>>(Wq, (unsigned short*)wqb, nw);
    pack_bf16<<<nw / (256 * 8), 256, 0, stream>>>(Wk, (unsigned short*)wkb, nw);
    pack_bf16<<<nw / (256 * 8), 256, 0, stream>>>(Wv, (unsigned short*)wvb, nw);

    dim3 grid(MROWS / BM, EMB / BN);
    gemm_bt<0><<<grid, 256, 0, stream>>>(xb, wqb, (unsigned short*)Qh, nullptr, nullptr, MROWS, EMB, EMB);
    gemm_bt<0><<<grid, 256, 0, stream>>>(xb, wkb, (unsigned short*)Kh, nullptr, nullptr, MROWS, EMB, EMB);

    diag_kernel<<<BATCH * HEADS * (SEQ / 128), 512, 0, stream>>>(Qh, Kh, dgp);

    gemm_bt<1><<<grid, 256, 0, stream>>>(xb, wvb, nullptr, out, dgp, MROWS, EMB, EMB);

    // output 1: x passthrough
    hipMemcpyAsync(out + (size_t)MROWS * EMB, x, (size_t)MROWS * EMB * sizeof(float),
                   hipMemcpyDeviceToDevice, stream);
}

// Round 3
// 154.201 us; speedup vs baseline: 2.2803x; 1.2359x over previous
//
#include <hip/hip_runtime.h>
#include <hip/hip_bf16.h>
#include <stdint.h>

typedef __attribute__((ext_vector_type(8))) short short8;
typedef __attribute__((ext_vector_type(4))) float f32x4;

// Problem constants
#define BATCH 4
#define SEQ   2048
#define EMB   1024
#define HEADS 16
#define DHEAD 64
#define MROWS (BATCH * SEQ)   // 8192

// exp(s/8) == exp2(s * 0.125*log2(e)); fold into Q at bf16-pack time
#define QSCALE 0.18033688011112042f

__device__ inline unsigned short f2bf(float f) {
    unsigned int u = __float_as_uint(f);
    unsigned int r = (u + 0x7fffu + ((u >> 16) & 1u)) >> 16;
    return (unsigned short)r;
}

__device__ __forceinline__ void gl_lds16(const short* g, short* l) {
    __builtin_amdgcn_global_load_lds(
        (const __attribute__((address_space(1))) void*)g,
        (__attribute__((address_space(3))) void*)l, 16, 0, 0);
}

// ---------------- fused pack x -> bf16 + f32 passthrough ----------------
__global__ __launch_bounds__(256) void pack_x(const float* __restrict__ src,
                                              unsigned short* __restrict__ dst,
                                              float* __restrict__ pass) {
    int i = (blockIdx.x * 256 + threadIdx.x) * 8;
    const float4* s = reinterpret_cast<const float4*>(src + i);
    float4 f0 = s[0];
    float4 f1 = s[1];
    union { unsigned short u[8]; short8 v; } o;
    o.u[0] = f2bf(f0.x); o.u[1] = f2bf(f0.y); o.u[2] = f2bf(f0.z); o.u[3] = f2bf(f0.w);
    o.u[4] = f2bf(f1.x); o.u[5] = f2bf(f1.y); o.u[6] = f2bf(f1.z); o.u[7] = f2bf(f1.w);
    *reinterpret_cast<short8*>(dst + i) = o.v;
    float4* p = reinterpret_cast<float4*>(pass + i);
    p[0] = f0;
    p[1] = f1;
}

// ---------------- pack 3 weights -> bf16, one dispatch ----------------
__global__ __launch_bounds__(256) void pack_w3(const float* __restrict__ wq,
                                               const float* __restrict__ wk,
                                               const float* __restrict__ wv,
                                               unsigned short* __restrict__ dq,
                                               unsigned short* __restrict__ dk,
                                               unsigned short* __restrict__ dv) {
    const float* src = blockIdx.y == 0 ? wq : blockIdx.y == 1 ? wk : wv;
    unsigned short* dst = blockIdx.y == 0 ? dq : blockIdx.y == 1 ? dk : dv;
    int i = (blockIdx.x * 256 + threadIdx.x) * 8;
    const float4* s = reinterpret_cast<const float4*>(src + i);
    float4 f0 = s[0];
    float4 f1 = s[1];
    union { unsigned short u[8]; short8 v; } o;
    o.u[0] = f2bf(f0.x); o.u[1] = f2bf(f0.y); o.u[2] = f2bf(f0.z); o.u[3] = f2bf(f0.w);
    o.u[4] = f2bf(f1.x); o.u[5] = f2bf(f1.y); o.u[6] = f2bf(f1.z); o.u[7] = f2bf(f1.w);
    *reinterpret_cast<short8*>(dst + i) = o.v;
}

// ---------------- GEMM (m97 structure): C[m,e] = sum_k A[m,k]*B[e,k] ----
// MODE 0: store bf16 head-major [B*H][SEQ][DHEAD], scaled by escale.
// MODE 1: store f32 to out, scaled by diag.
template <int MODE>
__global__ __launch_bounds__(256) void gemm_bt(const short* __restrict__ A,
                                               const short* __restrict__ Bm,
                                               unsigned short* __restrict__ Cb,
                                               float* __restrict__ out,
                                               const float* __restrict__ dgp,
                                               float escale) {
    constexpr int K = EMB;
    constexpr int N = EMB;
    __shared__ short As[128 * 32];   // linear: global_load_lds needs lane-contiguous dest
    __shared__ short Bs[128 * 32];
    const int m0 = blockIdx.x * 128;
    const int n0 = blockIdx.y * 128;
    const int t = threadIdx.x;
    const int lane = t & 63;
    const int w = t >> 6;                // 4 waves
    const int wr = w >> 1, wc = w & 1;   // 2x2 wave grid, 64x64 per wave

    f32x4 acc[4][4] = {};

    // staging: thread t covers row t>>2, shorts (t&3)*8..+8; +64 rows on inst 1
    const short* gA = A + (size_t)(m0 + (t >> 2)) * K + (t & 3) * 8;
    const short* gB = Bm + (size_t)(n0 + (t >> 2)) * K + (t & 3) * 8;
    short* lA0 = As + w * 512;           // wave-uniform LDS bases
    short* lA1 = As + 2048 + w * 512;
    short* lB0 = Bs + w * 512;
    short* lB1 = Bs + 2048 + w * 512;

    const int kq = (lane >> 4) * 8;
    const int fr = lane & 15;

    for (int k0 = 0; k0 < K; k0 += 32) {
        gl_lds16(gA + k0, lA0);
        gl_lds16(gA + 64 * K + k0, lA1);
        gl_lds16(gB + k0, lB0);
        gl_lds16(gB + 64 * K + k0, lB1);
        __syncthreads();   // compiler drains vmcnt(0) before s_barrier

        short8 a[4], b[4];
#pragma unroll
        for (int i = 0; i < 4; i++)
            a[i] = *(const short8*)&As[(wr * 64 + i * 16 + fr) * 32 + kq];
#pragma unroll
        for (int j = 0; j < 4; j++)
            b[j] = *(const short8*)&Bs[(wc * 64 + j * 16 + fr) * 32 + kq];
#pragma unroll
        for (int i = 0; i < 4; i++)
#pragma unroll
            for (int j = 0; j < 4; j++)
                acc[i][j] = __builtin_amdgcn_mfma_f32_16x16x32_bf16(a[i], b[j], acc[i][j], 0, 0, 0);
        __syncthreads();   // protect LDS before next stage overwrites
    }

    // epilogue: C layout col = lane&15, row = 4*(lane>>4)+r
    const int gr_base = m0 + wr * 64 + (lane >> 4) * 4;
    const int gc_base = n0 + wc * 64 + fr;
#pragma unroll
    for (int i = 0; i < 4; i++) {
#pragma unroll
        for (int j = 0; j < 4; j++) {
            const int col = gc_base + j * 16;
#pragma unroll
            for (int r = 0; r < 4; r++) {
                const int grow = gr_base + i * 16 + r;
                const int bb = grow >> 11;
                const int nn = grow & 2047;
                const int hh = col >> 6;
                if (MODE == 0) {
                    const int dd = col & 63;
                    Cb[(((size_t)((bb << 4) + hh) * SEQ + nn) << 6) + dd] =
                        f2bf(acc[i][j][r] * escale);
                } else {
                    const float d = dgp[((bb << 4) + hh) * SEQ + nn];
                    out[(size_t)grow * N + col] = acc[i][j][r] * d;
                }
            }
        }
    }
}

// ---------------- diag kernel v3 ----------------------------------------
// Qh/Kh head-major [64][2048][64] bf16 (Q pre-scaled by QSCALE).
// Block = (bh, 128-q-row tile), 512 threads = 8 waves x 16 q-rows.
// K staged in XOR-swizzled LDS tiles (row stride 128B, blk ^= row&7),
// double-buffered; diag[n] = exp2(s_nn) / sum_m exp2(s_nm).
#define KT 128

__global__ __launch_bounds__(512) void diag_kernel(const short* __restrict__ Qh,
                                                   const short* __restrict__ Kh,
                                                   float* __restrict__ dgp) {
    const int bh = blockIdx.x >> 4;     // 0..63
    const int qt = blockIdx.x & 15;     // 16 q-tiles of 128 rows
    __shared__ short Ks[2][KT][64];

    const int t = threadIdx.x;
    const int lane = t & 63;
    const int w = t >> 6;               // 0..7
    const int rl = lane & 15;
    const int g = lane >> 4;            // 0..3
    const int kq = g * 8;

    const short* Kbh = Kh + (size_t)bh * SEQ * DHEAD;
    const short* Qbh = Qh + (size_t)bh * SEQ * DHEAD;

    // Q fragments for this wave's 16 rows
    const int qrow = qt * 128 + w * 16 + rl;
    const short8 a0 = *(const short8*)(Qbh + qrow * DHEAD + kq);
    const short8 a1 = *(const short8*)(Qbh + qrow * DHEAD + kq + 32);

    // staging map: 512 threads cover 128 rows x 64 cols in 2 short8 each
    const int r0 = t >> 3;              // 0..63 (and +64)
    const int c0 = t & 7;               // 16B block 0..7
    const int cs = (c0 ^ (r0 & 7)) * 8; // XOR-swizzled block (shorts)

    // stage tile 0
    *(short8*)&Ks[0][r0][cs]      = *(const short8*)&Kbh[r0 * DHEAD + c0 * 8];
    *(short8*)&Ks[0][r0 + 64][cs] = *(const short8*)&Kbh[(r0 + 64) * DHEAD + c0 * 8];
    __syncthreads();

    // swizzled read blocks: logical block g (b0) and g+4 (b1), row&7 == lane&7
    const int blk0 = (g ^ (lane & 7)) * 8;
    const int blk1 = ((g + 4) ^ (lane & 7)) * 8;

    float ssum[4] = {0.f, 0.f, 0.f, 0.f};
    float sdiag = 0.f;
    int buf = 0;

    for (int kt = 0; kt < SEQ / KT; ++kt) {
        short8 p0, p1;
        if (kt < SEQ / KT - 1) {
            const short* src = Kbh + (kt + 1) * KT * DHEAD;
            p0 = *(const short8*)&src[r0 * DHEAD + c0 * 8];
            p1 = *(const short8*)&src[(r0 + 64) * DHEAD + c0 * 8];
        }
#pragma unroll
        for (int sub = 0; sub < 8; ++sub) {
            const int row = sub * 16 + rl;
            const short8 b0 = *(const short8*)&Ks[buf][row][blk0];
            const short8 b1 = *(const short8*)&Ks[buf][row][blk1];
            f32x4 c = {};
            c = __builtin_amdgcn_mfma_f32_16x16x32_bf16(a0, b0, c, 0, 0, 0);
            c = __builtin_amdgcn_mfma_f32_16x16x32_bf16(a1, b1, c, 0, 0, 0);
            if (kt == qt && sub == w) {
                const int r = rl - g * 4;
                if (r >= 0 && r < 4) sdiag = c[r];
            }
#pragma unroll
            for (int r = 0; r < 4; ++r)
                ssum[r] += __builtin_amdgcn_exp2f(c[r]);
        }
        if (kt < SEQ / KT - 1) {
            __syncthreads();
            *(short8*)&Ks[buf ^ 1][r0][cs]      = p0;
            *(short8*)&Ks[buf ^ 1][r0 + 64][cs] = p1;
            __syncthreads();
        }
        buf ^= 1;
    }

    // reduce partial sums across the 16-lane column groups
#pragma unroll
    for (int r = 0; r < 4; r++) {
        float v = ssum[r];
        v += __shfl_xor(v, 1);
        v += __shfl_xor(v, 2);
        v += __shfl_xor(v, 4);
        v += __shfl_xor(v, 8);
        ssum[r] = v;
    }

    const int j = rl;
    const int r = j - g * 4;
    if (r >= 0 && r < 4) {
        const float dg = __builtin_amdgcn_exp2f(sdiag) / ssum[r];
        dgp[bh * SEQ + qt * 128 + w * 16 + j] = dg;
    }
}

extern "C" void kernel_launch(void* const* d_in, const int* in_sizes, int n_in,
                              void* d_out, int out_size, void* d_ws, size_t ws_size,
                              hipStream_t stream) {
    const float* x  = (const float*)d_in[0];
    const float* Wq = (const float*)d_in[1];
    const float* Wk = (const float*)d_in[2];
    const float* Wv = (const float*)d_in[3];
    float* out = (float*)d_out;
    char* ws = (char*)d_ws;

    const size_t xb_off  = 0;
    const size_t wq_off  = xb_off + (size_t)MROWS * EMB * 2;
    const size_t wk_off  = wq_off + (size_t)EMB * EMB * 2;
    const size_t wv_off  = wk_off + (size_t)EMB * EMB * 2;
    const size_t q_off   = wv_off + (size_t)EMB * EMB * 2;
    const size_t k_off   = q_off + (size_t)MROWS * EMB * 2;
    const size_t dg_off  = k_off + (size_t)MROWS * EMB * 2;

    short* xb  = (short*)(ws + xb_off);
    short* wqb = (short*)(ws + wq_off);
    short* wkb = (short*)(ws + wk_off);
    short* wvb = (short*)(ws + wv_off);
    short* Qh  = (short*)(ws + q_off);
    short* Kh  = (short*)(ws + k_off);
    float* dgp = (float*)(ws + dg_off);

    const int nx = MROWS * EMB;    // 8388608
    const int nw = EMB * EMB;      // 1048576

    // pack x + write f32 passthrough (output 1) in one pass
    pack_x<<<nx / 2048, 256, 0, stream>>>(x, (unsigned short*)xb,
                                          out + (size_t)MROWS * EMB);
    pack_w3<<<dim3(nw / 2048, 3), 256, 0, stream>>>(Wq, Wk, Wv,
                                                    (unsigned short*)wqb,
                                                    (unsigned short*)wkb,
                                                    (unsigned short*)wvb);

    dim3 grid(MROWS / 128, EMB / 128);
    gemm_bt<0><<<grid, 256, 0, stream>>>(xb, wqb, (unsigned short*)Qh, nullptr, nullptr, QSCALE);
    gemm_bt<0><<<grid, 256, 0, stream>>>(xb, wkb, (unsigned short*)Kh, nullptr, nullptr, 1.0f);

    diag_kernel<<<BATCH * HEADS * (SEQ / 128), 512, 0, stream>>>(Qh, Kh, dgp);

    gemm_bt<1><<<grid, 256, 0, stream>>>(xb, wvb, nullptr, out, dgp, 1.0f);
}